// Round 2
// baseline (520.787 us; speedup 1.0000x reference)
//
#include <hip/hip_runtime.h>

// QRNN fo-pool: T=65536, E=512, H=512 (kernel_size=2)
// gates[T,1536] = concat(x, shift(x)) @ W + b ; z=tanh, f,o=sigmoid
// c_t = f_t c_{t-1} + (1-f_t) z_t ; h_t = o_t c_t
// out = [hiddens (T*512) | h_last (512) | c_last (512)]  (f32)

#define T_LEN 65536
#define H3    1536
#define NT    16            // K tiles of 64 (K=1024)
#define LC    64
#define NCHUNK 1024

typedef float f32x4 __attribute__((ext_vector_type(4)));
typedef short bf16x8 __attribute__((ext_vector_type(8)));

__device__ __forceinline__ unsigned short f2bf(float f) {
    unsigned int x = __builtin_bit_cast(unsigned int, f);
    x += 0x7fffu + ((x >> 16) & 1u);
    return (unsigned short)(x >> 16);
}
__device__ __forceinline__ float bf2f(unsigned short u) {
    return __builtin_bit_cast(float, ((unsigned int)u) << 16);
}
__device__ __forceinline__ float fsig(float x)  { return 1.f / (1.f + __expf(-x)); }
__device__ __forceinline__ float ftanh(float x) { return 2.f / (1.f + __expf(-2.f * x)) - 1.f; }

__device__ __forceinline__ void gload_lds16(const void* g, void* l) {
    __builtin_amdgcn_global_load_lds((const __attribute__((address_space(1))) void*)g,
                                     (__attribute__((address_space(3))) void*)l, 16, 0, 0);
}

#define SB()    __builtin_amdgcn_sched_barrier(0)
#define BARX()  __builtin_amdgcn_s_barrier()
#define LGKM0() asm volatile("s_waitcnt lgkmcnt(0)" ::: "memory")

// ---- prep: x (f32) -> bf16 with 512-element zero prefix ------------------
__global__ void prep_x(const float* __restrict__ x, unsigned short* __restrict__ xp) {
    const long long nq = (512LL + (long long)T_LEN * 512) / 4;
    for (long long q = (long long)blockIdx.x * blockDim.x + threadIdx.x; q < nq;
         q += (long long)gridDim.x * blockDim.x) {
        ushort4 u;
        if (q < 128) {
            u.x = 0; u.y = 0; u.z = 0; u.w = 0;
        } else {
            const float4 v = *reinterpret_cast<const float4*>(x + q * 4 - 512);
            u.x = f2bf(v.x); u.y = f2bf(v.y); u.z = f2bf(v.z); u.w = f2bf(v.w);
        }
        *reinterpret_cast<ushort4*>(xp + q * 4) = u;
    }
}

// ---- prep: W [1024,1536] f32 -> Wt [1536,1024] bf16 ----------------------
__global__ void prep_w(const float* __restrict__ W, unsigned short* __restrict__ Wt) {
    const int n_el = 1024 * H3;
    for (int i = blockIdx.x * blockDim.x + threadIdx.x; i < n_el;
         i += gridDim.x * blockDim.x) {
        const int k = i / H3, n = i - k * H3;
        Wt[n * 1024 + k] = f2bf(W[i]);
    }
}

// ---- GEMM: 256x256 tile, BK=64, 8 waves, 8-phase counted-vmcnt pipeline --
// LDS layout: lds[buf(2)][slot(4)][8192 bf16]; slot 0/1 = A rows 0-127/128-255,
// slot 2/3 = B rows 0-127/128-255. Half-tile = [128 rows][64 k] bf16, 128B/row,
// XOR-swizzled byte^=((row&7)<<4) via pre-swizzled global source (linear LDS dest).
#define RD_A(m, ks) (*(const bf16x8*)(ldsAr + bo + ((m)*16 + arow)*64 + ((ks) ? colel1 : colel0)))
#define RD_B(n, ks) (*(const bf16x8*)(ldsBr + bo + ((n)*16 + arow)*64 + ((ks) ? colel1 : colel0)))

#define QUAD(mh, nh)                                                                     \
    _Pragma("unroll")                                                                    \
    for (int mm = 0; mm < 4; ++mm) {                                                     \
        _Pragma("unroll")                                                                \
        for (int nn = 0; nn < 2; ++nn) {                                                 \
            acc[(mh)*4+mm][(nh)*2+nn] = __builtin_amdgcn_mfma_f32_16x16x32_bf16(         \
                a[(mh)*4+mm][0], b[(nh)*2+nn][0], acc[(mh)*4+mm][(nh)*2+nn], 0, 0, 0);   \
            acc[(mh)*4+mm][(nh)*2+nn] = __builtin_amdgcn_mfma_f32_16x16x32_bf16(         \
                a[(mh)*4+mm][1], b[(nh)*2+nn][1], acc[(mh)*4+mm][(nh)*2+nn], 0, 0, 0);   \
        }                                                                                \
    }

__global__ __launch_bounds__(512, 2) void gemm_gates(
    const unsigned short* __restrict__ xp,
    const unsigned short* __restrict__ Wt,
    const float* __restrict__ bias,
    unsigned short* __restrict__ zfo)
{
    __shared__ unsigned short lds[2 * 4 * 8192];   // 128 KiB

    const int tid  = threadIdx.x;
    const int lane = tid & 63;
    const int wid  = tid >> 6;           // 0..7
    const int wm   = wid >> 2;           // 0..1
    const int wn   = wid & 3;            // 0..3

    const int bn0 = blockIdx.x * 256;    // N base (0..1280)
    const int bm0 = blockIdx.y * 256;    // M base

    // staging geometry: thread covers 16B at linear half-tile byte (i*8192 + tid*16)
    const int srow = tid >> 3;                                  // row within 64-row group
    const int scol = (((tid & 7) ^ ((tid >> 3) & 7)) * 8);      // pre-swizzled col (elems)
    const int aoff = (bm0 + srow) * 512 + scol;
    const int boff = (bn0 + srow) * 1024 + scol;
    unsigned short* ldsw = (unsigned short*)lds + wid * 512;    // + (buf*4+s)*8192 + i*4096

    auto stageA = [&](int bb, int s, int kb) {
        const int abase = (kb < 512) ? (512 + kb) : (kb - 512);
        const unsigned short* g = xp + abase + aoff + s * (128 * 512);
        unsigned short* l = ldsw + (bb * 4 + s) * 8192;
        gload_lds16(g, l);
        gload_lds16(g + 64 * 512, l + 4096);
    };
    auto stageB = [&](int bb, int s, int kb) {
        const unsigned short* g = Wt + boff + kb + s * (128 * 1024);
        unsigned short* l = ldsw + (bb * 4 + 2 + s) * 8192;
        gload_lds16(g, l);
        gload_lds16(g + 64 * 1024, l + 4096);
    };

    // fragment read geometry (swizzled read matches staged involution)
    const int arow   = lane & 15;
    const int colel0 = (((lane >> 4) * 16)      ^ ((lane & 7) << 4)) >> 1;
    const int colel1 = ((64 + (lane >> 4) * 16) ^ ((lane & 7) << 4)) >> 1;
    const unsigned short* ldsAr = (const unsigned short*)lds + wm * 8192;
    const unsigned short* ldsBr = (const unsigned short*)lds + (2 + (wn >> 1)) * 8192 + (wn & 1) * 4096;

    f32x4  acc[8][4] = {};
    bf16x8 a[8][2]   = {};
    bf16x8 b[4][2]   = {};

    // prologue: stage tile0 (4 halves) + tile1 slots 0..2 -> 14 loads/wave
    stageA(0, 0, 0);  stageA(0, 1, 0);  stageB(0, 0, 0);  stageB(0, 1, 0);
    stageA(1, 0, 64); stageA(1, 1, 64); stageB(1, 0, 64);
    asm volatile("s_waitcnt vmcnt(6)" ::: "memory");   // tile0 resident, 3 halves in flight
    SB(); BARX(); SB();

    for (int t = 0; t < NT; ++t) {
        const int buf = t & 1;
        const int bo  = buf * 32768;

        // ---- phase 0: quadrant (0,0) -----------------------------------
        {
            #pragma unroll
            for (int m = 0; m < 4; ++m) { a[m][0] = RD_A(m, 0); a[m][1] = RD_A(m, 1); }
            if (wm == 0) {
                #pragma unroll
                for (int m = 4; m < 8; ++m) { a[m][0] = RD_A(m, 0); a[m][1] = RD_A(m, 1); }
            }
            #pragma unroll
            for (int n = 0; n < 2; ++n) { b[n][0] = RD_B(n, 0); b[n][1] = RD_B(n, 1); }
            if (t + 1 < NT) stageB(buf ^ 1, 1, (t + 1) * 64);   // tile t+1 slot 3
            SB(); BARX(); SB();
            LGKM0(); SB();
            __builtin_amdgcn_s_setprio(1);
            QUAD(0, 0);
            __builtin_amdgcn_s_setprio(0);
            SB(); BARX(); SB();
        }
        // ---- phase 1: quadrant (0,1) -----------------------------------
        {
            if (wm == 1) {
                #pragma unroll
                for (int m = 4; m < 8; ++m) { a[m][0] = RD_A(m, 0); a[m][1] = RD_A(m, 1); }
            }
            #pragma unroll
            for (int n = 2; n < 4; ++n) { b[n][0] = RD_B(n, 0); b[n][1] = RD_B(n, 1); }
            if (t + 2 < NT) stageA(buf, 0, (t + 2) * 64);       // tile t+2 slot 0
            SB(); BARX(); SB();
            LGKM0(); SB();
            __builtin_amdgcn_s_setprio(1);
            QUAD(0, 1);
            __builtin_amdgcn_s_setprio(0);
            SB(); BARX(); SB();
        }
        // ---- phase 2: quadrant (1,0) -----------------------------------
        {
            if (t + 2 < NT) stageA(buf, 1, (t + 2) * 64);       // tile t+2 slot 1
            SB(); BARX(); SB();
            __builtin_amdgcn_s_setprio(1);
            QUAD(1, 0);
            __builtin_amdgcn_s_setprio(0);
            SB(); BARX(); SB();
        }
        // ---- phase 3: quadrant (1,1) + vmcnt gate -----------------------
        {
            if (t + 2 < NT) stageB(buf, 0, (t + 2) * 64);       // tile t+2 slot 2
            SB(); BARX(); SB();
            __builtin_amdgcn_s_setprio(1);
            QUAD(1, 1);
            __builtin_amdgcn_s_setprio(0);
            if (t < NT - 2)       { asm volatile("s_waitcnt vmcnt(6)" ::: "memory"); }
            else if (t == NT - 2) { asm volatile("s_waitcnt vmcnt(0)" ::: "memory"); }
            SB(); BARX(); SB();
        }
    }

    // epilogue: bias + activation (class uniform per block), bf16 store
    const int cls   = bn0 >> 9;          // 0=z(tanh), 1=f, 2=o (sigmoid)
    const int r0    = bm0 + wm * 128 + ((lane >> 4) << 2);
    const int cbase = bn0 + wn * 64 + (lane & 15);
    #pragma unroll
    for (int n = 0; n < 4; ++n) {
        const int col = cbase + n * 16;
        const float bn_ = bias[col];
        #pragma unroll
        for (int m = 0; m < 8; ++m) {
            const int row = r0 + m * 16;
            #pragma unroll
            for (int j = 0; j < 4; ++j) {
                float v = acc[m][n][j] + bn_;
                v = (cls == 0) ? ftanh(v) : fsig(v);
                zfo[(row + j) * H3 + col] = f2bf(v);
            }
        }
    }
}

// ---- scan pass 1: per-chunk local scan (c_init=0) + product of f ---------
// 1024 chunks of 64 steps; 128 threads/block, 4 channels/thread (ushort4 loads)
__global__ void scan_pass1(const unsigned short* __restrict__ zfo,
                           float* __restrict__ P, float* __restrict__ L) {
    const int chunk = blockIdx.x;
    const int c4    = threadIdx.x;           // 0..127
    const unsigned short* base = zfo + (long long)chunk * LC * H3 + c4 * 4;
    float c[4] = {0.f, 0.f, 0.f, 0.f};
    float p[4] = {1.f, 1.f, 1.f, 1.f};
    for (int t = 0; t < LC; ++t) {
        const unsigned short* row = base + t * H3;
        const ushort4 uz = *reinterpret_cast<const ushort4*>(row);
        const ushort4 uf = *reinterpret_cast<const ushort4*>(row + 512);
        const float z[4] = {bf2f(uz.x), bf2f(uz.y), bf2f(uz.z), bf2f(uz.w)};
        const float f[4] = {bf2f(uf.x), bf2f(uf.y), bf2f(uf.z), bf2f(uf.w)};
        #pragma unroll
        for (int j = 0; j < 4; ++j) {
            c[j] = fmaf(f[j], c[j] - z[j], z[j]);   // f*c + (1-f)*z
            p[j] *= f[j];
        }
    }
    #pragma unroll
    for (int j = 0; j < 4; ++j) {
        P[chunk * 512 + c4 * 4 + j] = p[j];
        L[chunk * 512 + c4 * 4 + j] = c[j];
    }
}

// ---- scan pass 2: parallel affine-composition scan over chunks -----------
// one block per channel (512), 1024 threads = 1024 chunks, Hillis-Steele
__global__ __launch_bounds__(1024) void scan_pass2(
    const float* __restrict__ P, const float* __restrict__ L,
    float* __restrict__ carry, float* __restrict__ out) {
    const int ch = blockIdx.x;
    const int k  = threadIdx.x;
    __shared__ float sP[1024], sL[1024];
    float p = P[k * 512 + ch];
    float l = L[k * 512 + ch];
    sP[k] = p; sL[k] = l;
    __syncthreads();
    for (int d = 1; d < 1024; d <<= 1) {
        float pp = 1.f, ll = 0.f;
        if (k >= d) { pp = sP[k - d]; ll = sL[k - d]; }
        __syncthreads();
        l = fmaf(p, ll, l);
        p = p * pp;
        sP[k] = p; sL[k] = l;
        __syncthreads();
    }
    carry[k * 512 + ch] = (k == 0) ? 0.f : sL[k - 1];
    if (k == 1023) out[(long long)T_LEN * 512 + 512 + ch] = l;   // cells[-1]
}

// ---- scan pass 3: replay with carry-in, write h = o*c (float4 stores) ----
__global__ void scan_pass3(const unsigned short* __restrict__ zfo,
                           const float* __restrict__ carry,
                           float* __restrict__ out) {
    const int chunk = blockIdx.x;
    const int c4    = threadIdx.x;           // 0..127
    const unsigned short* base = zfo + (long long)chunk * LC * H3 + c4 * 4;
    float c[4], h[4] = {0.f, 0.f, 0.f, 0.f};
    #pragma unroll
    for (int j = 0; j < 4; ++j) c[j] = carry[chunk * 512 + c4 * 4 + j];
    float4* outp = reinterpret_cast<float4*>(out + (long long)chunk * LC * 512) + c4;
    for (int t = 0; t < LC; ++t) {
        const unsigned short* row = base + t * H3;
        const ushort4 uz = *reinterpret_cast<const ushort4*>(row);
        const ushort4 uf = *reinterpret_cast<const ushort4*>(row + 512);
        const ushort4 uo = *reinterpret_cast<const ushort4*>(row + 1024);
        const float z[4] = {bf2f(uz.x), bf2f(uz.y), bf2f(uz.z), bf2f(uz.w)};
        const float f[4] = {bf2f(uf.x), bf2f(uf.y), bf2f(uf.z), bf2f(uf.w)};
        const float o[4] = {bf2f(uo.x), bf2f(uo.y), bf2f(uo.z), bf2f(uo.w)};
        #pragma unroll
        for (int j = 0; j < 4; ++j) {
            c[j] = fmaf(f[j], c[j] - z[j], z[j]);
            h[j] = o[j] * c[j];
        }
        float4 hv; hv.x = h[0]; hv.y = h[1]; hv.z = h[2]; hv.w = h[3];
        outp[t * 128] = hv;
    }
    if (chunk == NCHUNK - 1) {
        #pragma unroll
        for (int j = 0; j < 4; ++j)
            out[(long long)T_LEN * 512 + c4 * 4 + j] = h[j];     // hiddens[-1]
    }
}

extern "C" void kernel_launch(void* const* d_in, const int* in_sizes, int n_in,
                              void* d_out, int out_size, void* d_ws, size_t ws_size,
                              hipStream_t stream) {
    const float* x = (const float*)d_in[0];   // [65536, 512]
    const float* W = (const float*)d_in[1];   // [1024, 1536]
    const float* b = (const float*)d_in[2];   // [1536]
    float* out = (float*)d_out;

    char* ws = (char*)d_ws;
    unsigned short* xp  = (unsigned short*)(ws);                 // 67,109,888 B (+pad)
    unsigned short* Wt  = (unsigned short*)(ws + 67110912LL);    // 3,145,728 B
    unsigned short* zfo = (unsigned short*)(ws + 70256640LL);    // 201,326,592 B -> ends 271,583,232
    // P/L/carry reuse the xp region (dead after GEMM): 2 MiB each
    float* P     = (float*)(ws);
    float* L     = (float*)(ws + 4194304LL);
    float* carry = (float*)(ws + 8388608LL);

    prep_x<<<4096, 256, 0, stream>>>(x, xp);
    prep_w<<<768, 256, 0, stream>>>(W, Wt);

    dim3 gg(H3 / 256, T_LEN / 256, 1);     // 6 x 256
    gemm_gates<<<gg, 512, 0, stream>>>(xp, Wt, b, zfo);

    scan_pass1<<<NCHUNK, 128, 0, stream>>>(zfo, P, L);
    scan_pass2<<<512, 1024, 0, stream>>>(P, L, carry, out);
    scan_pass3<<<NCHUNK, 128, 0, stream>>>(zfo, carry, out);
}

// Round 3
// 473.234 us; speedup vs baseline: 1.1005x; 1.1005x over previous
//
#include <hip/hip_runtime.h>

// QRNN fo-pool: T=65536, E=512, H=512 (kernel_size=2)
// gates[T,1536] = concat(x, shift(x)) @ W + b ; z=tanh, f,o=sigmoid
// c_t = f_t c_{t-1} + (1-f_t) z_t ; h_t = o_t c_t
// out = [hiddens (T*512) | h_last (512) | c_last (512)]  (f32)

#define T_LEN 65536
#define H3    1536
#define NT    16            // K tiles of 64 (K=1024)
#define LC    64
#define NCHUNK 1024

typedef float f32x4 __attribute__((ext_vector_type(4)));
typedef short bf16x8 __attribute__((ext_vector_type(8)));

__device__ __forceinline__ unsigned short f2bf(float f) {
    unsigned int x = __builtin_bit_cast(unsigned int, f);
    x += 0x7fffu + ((x >> 16) & 1u);
    return (unsigned short)(x >> 16);
}
__device__ __forceinline__ float bf2f(unsigned short u) {
    return __builtin_bit_cast(float, ((unsigned int)u) << 16);
}
__device__ __forceinline__ float fsig(float x)  { return 1.f / (1.f + __expf(-x)); }
__device__ __forceinline__ float ftanh(float x) { return 2.f / (1.f + __expf(-2.f * x)) - 1.f; }

__device__ __forceinline__ void gload_lds16(const void* g, void* l) {
    __builtin_amdgcn_global_load_lds((const __attribute__((address_space(1))) void*)g,
                                     (__attribute__((address_space(3))) void*)l, 16, 0, 0);
}

#define BARX()  __builtin_amdgcn_s_barrier()
#define LGKM0() asm volatile("s_waitcnt lgkmcnt(0)" ::: "memory")

// ---- prep: x (f32) -> bf16 with 512-element zero prefix ------------------
__global__ void prep_x(const float* __restrict__ x, unsigned short* __restrict__ xp) {
    const long long nq = (512LL + (long long)T_LEN * 512) / 4;
    for (long long q = (long long)blockIdx.x * blockDim.x + threadIdx.x; q < nq;
         q += (long long)gridDim.x * blockDim.x) {
        ushort4 u;
        if (q < 128) {
            u.x = 0; u.y = 0; u.z = 0; u.w = 0;
        } else {
            const float4 v = *reinterpret_cast<const float4*>(x + q * 4 - 512);
            u.x = f2bf(v.x); u.y = f2bf(v.y); u.z = f2bf(v.z); u.w = f2bf(v.w);
        }
        *reinterpret_cast<ushort4*>(xp + q * 4) = u;
    }
}

// ---- prep: W [1024,1536] f32 -> Wt [1536,1024] bf16 ----------------------
__global__ void prep_w(const float* __restrict__ W, unsigned short* __restrict__ Wt) {
    const int n_el = 1024 * H3;
    for (int i = blockIdx.x * blockDim.x + threadIdx.x; i < n_el;
         i += gridDim.x * blockDim.x) {
        const int k = i / H3, n = i - k * H3;
        Wt[n * 1024 + k] = f2bf(W[i]);
    }
}

// ---- GEMM: 256x256 tile, BK=64, 8 waves, 4-phase counted-vmcnt pipeline --
// LDS: lds[buf(2)][slot(4)][8192 bf16]; slot0/1 = A rows 0-127/128-255,
// slot2/3 = B rows 0-127/128-255. Half-tile [128r][64k], 128B/row, XOR-swizzle
// byte^=((row&7)<<4) via pre-swizzled global source (linear LDS dest, rule #21).
#define RD_A(m, ks) (*(const bf16x8*)(ldsAr + bo + ((m)*16 + arow)*64 + ((ks) ? colel1 : colel0)))
#define RD_B(n, ks) (*(const bf16x8*)(ldsBr + bo + ((n)*16 + arow)*64 + ((ks) ? colel1 : colel0)))

// quadrant: m-half mh (rows mh*4..mh*4+3 of acc), n-half nh (cols nh*2..+1)
#define QUAD(mh, nh)                                                                     \
    _Pragma("unroll")                                                                    \
    for (int mm = 0; mm < 4; ++mm) {                                                     \
        _Pragma("unroll")                                                                \
        for (int nn = 0; nn < 2; ++nn) {                                                 \
            acc[(mh)*4+mm][(nh)*2+nn] = __builtin_amdgcn_mfma_f32_16x16x32_bf16(         \
                a[(mh)*4+mm][0], b[(nh)*2+nn][0], acc[(mh)*4+mm][(nh)*2+nn], 0, 0, 0);   \
            acc[(mh)*4+mm][(nh)*2+nn] = __builtin_amdgcn_mfma_f32_16x16x32_bf16(         \
                a[(mh)*4+mm][1], b[(nh)*2+nn][1], acc[(mh)*4+mm][(nh)*2+nn], 0, 0, 0);   \
        }                                                                                \
    }

__global__ __launch_bounds__(512, 2) void gemm_gates(
    const unsigned short* __restrict__ xp,
    const unsigned short* __restrict__ Wt,
    const float* __restrict__ bias,
    unsigned short* __restrict__ zfo)
{
    __shared__ unsigned short lds[2 * 4 * 8192];   // 128 KiB

    const int tid  = threadIdx.x;
    const int lane = tid & 63;
    const int wid  = tid >> 6;           // 0..7
    const int wm   = wid >> 2;           // 0..1
    const int wn   = wid & 3;            // 0..3

    // XCD-chunked swizzle (T1): 1536 blocks, 8 XCDs, 192/XCD; the 6 blocks
    // sharing an A-panel become consecutive slots on ONE XCD (L2 reuse).
    const int flat = blockIdx.y * gridDim.x + blockIdx.x;
    const int idx  = (flat & 7) * 192 + (flat >> 3);
    const int bn0 = (idx % 6) * 256;     // N base (0..1280)
    const int bm0 = (idx / 6) * 256;     // M base

    // staging geometry: thread covers 16B at linear half-tile byte (i*8192 + tid*16)
    const int srow = tid >> 3;                                  // row within 64-row group
    const int scol = (((tid & 7) ^ ((tid >> 3) & 7)) * 8);      // pre-swizzled col (elems)
    const int aoff = (bm0 + srow) * 512 + scol;
    const int boff = (bn0 + srow) * 1024 + scol;
    unsigned short* ldsw = (unsigned short*)lds + wid * 512;    // + (buf*4+s)*8192 + i*4096

    auto stageA = [&](int bb, int s, int kb) {
        const int abase = (kb < 512) ? (512 + kb) : (kb - 512);
        const unsigned short* g = xp + abase + aoff + s * (128 * 512);
        unsigned short* l = ldsw + (bb * 4 + s) * 8192;
        gload_lds16(g, l);
        gload_lds16(g + 64 * 512, l + 4096);
    };
    auto stageB = [&](int bb, int s, int kb) {
        const unsigned short* g = Wt + boff + kb + s * (128 * 1024);
        unsigned short* l = ldsw + (bb * 4 + 2 + s) * 8192;
        gload_lds16(g, l);
        gload_lds16(g + 64 * 1024, l + 4096);
    };

    // fragment read geometry (swizzled read matches staged involution)
    const int arow   = lane & 15;
    const int colel0 = (((lane >> 4) * 16)      ^ ((lane & 7) << 4)) >> 1;
    const int colel1 = ((64 + (lane >> 4) * 16) ^ ((lane & 7) << 4)) >> 1;
    const unsigned short* ldsAr = (const unsigned short*)lds + wm * 8192;
    const unsigned short* ldsBr = (const unsigned short*)lds + (2 + (wn >> 1)) * 8192 + (wn & 1) * 4096;

    f32x4  acc[8][4] = {};
    bf16x8 a[8][2]   = {};
    bf16x8 b[4][2]   = {};

    // prologue: tile0 all 4 slots + tile1 slots 0,1,2 -> 14 loads/wave
    stageA(0, 0, 0);  stageA(0, 1, 0);  stageB(0, 0, 0);  stageB(0, 1, 0);
    stageA(1, 0, 64); stageA(1, 1, 64); stageB(1, 0, 64);
    asm volatile("s_waitcnt vmcnt(6)" ::: "memory");   // tile0 resident, 6 in flight
    BARX();

    for (int t = 0; t < NT; ++t) {
        const int buf = t & 1;
        const int bo  = buf * 32768;

        // ---- phase 0: reads a[0..3],b[0..1] (12); Q(m0-3, n0-1) ---------
        {
            #pragma unroll
            for (int m = 0; m < 4; ++m) { a[m][0] = RD_A(m, 0); a[m][1] = RD_A(m, 1); }
            #pragma unroll
            for (int n = 0; n < 2; ++n) { b[n][0] = RD_B(n, 0); b[n][1] = RD_B(n, 1); }
            if (t + 1 < NT) stageB(buf ^ 1, 1, (t + 1) * 64);   // tile t+1 slot 3
            BARX();
            LGKM0();
            __builtin_amdgcn_s_setprio(1);
            QUAD(0, 0);
            __builtin_amdgcn_s_setprio(0);
            BARX();
        }
        // ---- phase 1: reads a[4..7],b[2..3] (12); Q(m0-3, n2-3) ---------
        {
            #pragma unroll
            for (int m = 4; m < 8; ++m) { a[m][0] = RD_A(m, 0); a[m][1] = RD_A(m, 1); }
            #pragma unroll
            for (int n = 2; n < 4; ++n) { b[n][0] = RD_B(n, 0); b[n][1] = RD_B(n, 1); }
            BARX();
            LGKM0();
            __builtin_amdgcn_s_setprio(1);
            QUAD(0, 1);
            __builtin_amdgcn_s_setprio(0);
            BARX();
        }
        // ---- phase 2: stage t+2 A slots (reads of buf A done by ph1 bar) -
        {
            if (t + 2 < NT) { stageA(buf, 0, (t + 2) * 64); stageA(buf, 1, (t + 2) * 64); }
            BARX();
            __builtin_amdgcn_s_setprio(1);
            QUAD(1, 0);
            __builtin_amdgcn_s_setprio(0);
            BARX();
        }
        // ---- phase 3: stage t+2 B slot 2 + vmcnt gate --------------------
        {
            if (t + 2 < NT) stageB(buf, 0, (t + 2) * 64);
            BARX();
            __builtin_amdgcn_s_setprio(1);
            QUAD(1, 1);
            __builtin_amdgcn_s_setprio(0);
            if (t < NT - 2)       { asm volatile("s_waitcnt vmcnt(6)" ::: "memory"); }
            else if (t == NT - 2) { asm volatile("s_waitcnt vmcnt(0)" ::: "memory"); }
            BARX();
        }
    }

    // epilogue: bias + activation (class uniform per block), bf16 store
    const int cls   = bn0 >> 9;          // 0=z(tanh), 1=f, 2=o (sigmoid)
    const int r0    = bm0 + wm * 128 + ((lane >> 4) << 2);
    const int cbase = bn0 + wn * 64 + (lane & 15);
    #pragma unroll
    for (int n = 0; n < 4; ++n) {
        const int col = cbase + n * 16;
        const float bn_ = bias[col];
        #pragma unroll
        for (int m = 0; m < 8; ++m) {
            const int row = r0 + m * 16;
            #pragma unroll
            for (int j = 0; j < 4; ++j) {
                float v = acc[m][n][j] + bn_;
                v = (cls == 0) ? ftanh(v) : fsig(v);
                zfo[(row + j) * H3 + col] = f2bf(v);
            }
        }
    }
}

// ---- scan pass 1: per-chunk local scan (c_init=0) + product of f ---------
__global__ void scan_pass1(const unsigned short* __restrict__ zfo,
                           float* __restrict__ P, float* __restrict__ L) {
    const int chunk = blockIdx.x;
    const int c4    = threadIdx.x;           // 0..127
    const unsigned short* base = zfo + (long long)chunk * LC * H3 + c4 * 4;
    float c[4] = {0.f, 0.f, 0.f, 0.f};
    float p[4] = {1.f, 1.f, 1.f, 1.f};
    for (int t = 0; t < LC; ++t) {
        const unsigned short* row = base + t * H3;
        const ushort4 uz = *reinterpret_cast<const ushort4*>(row);
        const ushort4 uf = *reinterpret_cast<const ushort4*>(row + 512);
        const float z[4] = {bf2f(uz.x), bf2f(uz.y), bf2f(uz.z), bf2f(uz.w)};
        const float f[4] = {bf2f(uf.x), bf2f(uf.y), bf2f(uf.z), bf2f(uf.w)};
        #pragma unroll
        for (int j = 0; j < 4; ++j) {
            c[j] = fmaf(f[j], c[j] - z[j], z[j]);   // f*c + (1-f)*z
            p[j] *= f[j];
        }
    }
    #pragma unroll
    for (int j = 0; j < 4; ++j) {
        P[chunk * 512 + c4 * 4 + j] = p[j];
        L[chunk * 512 + c4 * 4 + j] = c[j];
    }
}

// ---- scan pass 2: parallel affine-composition scan over chunks -----------
__global__ __launch_bounds__(1024) void scan_pass2(
    const float* __restrict__ P, const float* __restrict__ L,
    float* __restrict__ carry, float* __restrict__ out) {
    const int ch = blockIdx.x;
    const int k  = threadIdx.x;
    __shared__ float sP[1024], sL[1024];
    float p = P[k * 512 + ch];
    float l = L[k * 512 + ch];
    sP[k] = p; sL[k] = l;
    __syncthreads();
    for (int d = 1; d < 1024; d <<= 1) {
        float pp = 1.f, ll = 0.f;
        if (k >= d) { pp = sP[k - d]; ll = sL[k - d]; }
        __syncthreads();
        l = fmaf(p, ll, l);
        p = p * pp;
        sP[k] = p; sL[k] = l;
        __syncthreads();
    }
    carry[k * 512 + ch] = (k == 0) ? 0.f : sL[k - 1];
    if (k == 1023) out[(long long)T_LEN * 512 + 512 + ch] = l;   // cells[-1]
}

// ---- scan pass 3: replay with carry-in, write h = o*c (float4 stores) ----
__global__ void scan_pass3(const unsigned short* __restrict__ zfo,
                           const float* __restrict__ carry,
                           float* __restrict__ out) {
    const int chunk = blockIdx.x;
    const int c4    = threadIdx.x;           // 0..127
    const unsigned short* base = zfo + (long long)chunk * LC * H3 + c4 * 4;
    float c[4], h[4] = {0.f, 0.f, 0.f, 0.f};
    #pragma unroll
    for (int j = 0; j < 4; ++j) c[j] = carry[chunk * 512 + c4 * 4 + j];
    float4* outp = reinterpret_cast<float4*>(out + (long long)chunk * LC * 512) + c4;
    for (int t = 0; t < LC; ++t) {
        const unsigned short* row = base + t * H3;
        const ushort4 uz = *reinterpret_cast<const ushort4*>(row);
        const ushort4 uf = *reinterpret_cast<const ushort4*>(row + 512);
        const ushort4 uo = *reinterpret_cast<const ushort4*>(row + 1024);
        const float z[4] = {bf2f(uz.x), bf2f(uz.y), bf2f(uz.z), bf2f(uz.w)};
        const float f[4] = {bf2f(uf.x), bf2f(uf.y), bf2f(uf.z), bf2f(uf.w)};
        const float o[4] = {bf2f(uo.x), bf2f(uo.y), bf2f(uo.z), bf2f(uo.w)};
        #pragma unroll
        for (int j = 0; j < 4; ++j) {
            c[j] = fmaf(f[j], c[j] - z[j], z[j]);
            h[j] = o[j] * c[j];
        }
        float4 hv; hv.x = h[0]; hv.y = h[1]; hv.z = h[2]; hv.w = h[3];
        outp[t * 128] = hv;
    }
    if (chunk == NCHUNK - 1) {
        #pragma unroll
        for (int j = 0; j < 4; ++j)
            out[(long long)T_LEN * 512 + c4 * 4 + j] = h[j];     // hiddens[-1]
    }
}

extern "C" void kernel_launch(void* const* d_in, const int* in_sizes, int n_in,
                              void* d_out, int out_size, void* d_ws, size_t ws_size,
                              hipStream_t stream) {
    const float* x = (const float*)d_in[0];   // [65536, 512]
    const float* W = (const float*)d_in[1];   // [1024, 1536]
    const float* b = (const float*)d_in[2];   // [1536]
    float* out = (float*)d_out;

    char* ws = (char*)d_ws;
    unsigned short* xp  = (unsigned short*)(ws);                 // 67,109,888 B (+pad)
    unsigned short* Wt  = (unsigned short*)(ws + 67110912LL);    // 3,145,728 B
    unsigned short* zfo = (unsigned short*)(ws + 70256640LL);    // 201,326,592 B
    // P/L/carry reuse the xp region (dead after GEMM)
    float* P     = (float*)(ws);
    float* L     = (float*)(ws + 4194304LL);
    float* carry = (float*)(ws + 8388608LL);

    prep_x<<<4096, 256, 0, stream>>>(x, xp);
    prep_w<<<768, 256, 0, stream>>>(W, Wt);

    dim3 gg(H3 / 256, T_LEN / 256, 1);     // 6 x 256
    gemm_gates<<<gg, 512, 0, stream>>>(xp, Wt, b, zfo);

    scan_pass1<<<NCHUNK, 128, 0, stream>>>(zfo, P, L);
    scan_pass2<<<512, 1024, 0, stream>>>(P, L, carry, out);
    scan_pass3<<<NCHUNK, 128, 0, stream>>>(zfo, carry, out);
}

// Round 4
// 442.346 us; speedup vs baseline: 1.1773x; 1.0698x over previous
//
#include <hip/hip_runtime.h>

// QRNN fo-pool: T=65536, E=512, H=512 (kernel_size=2)
// gates[T,1536] = concat(x, shift(x)) @ W + b ; z=tanh, f,o=sigmoid
// c_t = f_t c_{t-1} + (1-f_t) z_t ; h_t = o_t c_t
// out = [hiddens (T*512) | h_last (512) | c_last (512)]  (f32)

#define T_LEN 65536
#define H3    1536
#define LC    64
#define NCHUNK 1024

typedef float f32x4 __attribute__((ext_vector_type(4)));
typedef short bf16x8 __attribute__((ext_vector_type(8)));

__device__ __forceinline__ unsigned short f2bf(float f) {
    unsigned int x = __builtin_bit_cast(unsigned int, f);
    x += 0x7fffu + ((x >> 16) & 1u);
    return (unsigned short)(x >> 16);
}
__device__ __forceinline__ float bf2f(unsigned short u) {
    return __builtin_bit_cast(float, ((unsigned int)u) << 16);
}
__device__ __forceinline__ float fsig(float x)  { return 1.f / (1.f + __expf(-x)); }
__device__ __forceinline__ float ftanh(float x) { return 2.f / (1.f + __expf(-2.f * x)) - 1.f; }

__device__ __forceinline__ void gload_lds16(const void* g, void* l) {
    __builtin_amdgcn_global_load_lds((const __attribute__((address_space(1))) void*)g,
                                     (__attribute__((address_space(3))) void*)l, 16, 0, 0);
}

// ---- prep: x (f32) -> bf16 with 512-element zero prefix ------------------
__global__ void prep_x(const float* __restrict__ x, unsigned short* __restrict__ xp) {
    const long long nq = (512LL + (long long)T_LEN * 512) / 4;
    for (long long q = (long long)blockIdx.x * blockDim.x + threadIdx.x; q < nq;
         q += (long long)gridDim.x * blockDim.x) {
        ushort4 u;
        if (q < 128) {
            u.x = 0; u.y = 0; u.z = 0; u.w = 0;
        } else {
            const float4 v = *reinterpret_cast<const float4*>(x + q * 4 - 512);
            u.x = f2bf(v.x); u.y = f2bf(v.y); u.z = f2bf(v.z); u.w = f2bf(v.w);
        }
        *reinterpret_cast<ushort4*>(xp + q * 4) = u;
    }
}

// ---- prep: W [1024,1536] f32 -> Wt [1536,1024] bf16 ----------------------
__global__ void prep_w(const float* __restrict__ W, unsigned short* __restrict__ Wt) {
    const int n_el = 1024 * H3;
    for (int i = blockIdx.x * blockDim.x + threadIdx.x; i < n_el;
         i += gridDim.x * blockDim.x) {
        const int k = i / H3, n = i - k * H3;
        Wt[n * 1024 + k] = f2bf(W[i]);
    }
}

// ---- GEMM: 128x128 tile, BK=32, 4 waves, 2-phase prefetch ----------------
// LDS: A/B double-buffered [2][128*32] bf16 (8 KiB each half). Rows are 64 B.
// XOR swizzle: 16B-slot s' = s ^ ((row>>1)&3), applied via pre-swizzled global
// source (linear LDS dest) + swizzled read (rule #21; same involution).
__global__ __launch_bounds__(256) void gemm_gates(
    const unsigned short* __restrict__ xp,
    const unsigned short* __restrict__ Wt,
    const float* __restrict__ bias,
    unsigned short* __restrict__ zfo)
{
    __shared__ unsigned short Alds[2][128 * 32];
    __shared__ unsigned short Blds[2][128 * 32];

    const int tid  = threadIdx.x;
    const int lane = tid & 63;
    const int w    = tid >> 6;           // wave 0..3
    const int wr   = w >> 1, wc = w & 1; // 2x2 wave grid, 64x64 each

    // XCD-chunked swizzle (T1): 6144 blocks, 8 XCDs, 768/XCD; the 12 blocks
    // sharing an A-panel land consecutively on ONE XCD; B (3 MB) L2-resident.
    const int flat = blockIdx.y * gridDim.x + blockIdx.x;   // 0..6143
    const int idx  = (flat & 7) * 768 + (flat >> 3);
    const int nb   = (idx % 12) * 128;                      // N base
    const long long t0 = (long long)(idx / 12) * 128;       // M base (time rows)

    // staging geometry: per wave, gload dest = base + lane*16B (wave-uniform base).
    // chunk rows j*64 + w*16 + (lane>>2); 16B slot = lane&3, pre-swizzled source col.
    const int srow_l = lane >> 2;                               // 0..15 row in 16-group
    const int scol   = (((lane & 3) ^ ((lane >> 3) & 3)) * 8);  // swizzled col (elems)

    auto stage = [&](int bb, int kt) {
        const int kb = kt * 32;
        const long long abase = (kb < 512) ? (long long)(512 + kb) : (long long)(kb - 512);
        #pragma unroll
        for (int j = 0; j < 2; ++j) {
            const int row = j * 64 + w * 16 + srow_l;           // 0..127
            gload_lds16(xp + abase + (t0 + row) * 512 + scol,
                        &Alds[bb][(j * 64 + w * 16) * 32]);
            gload_lds16(Wt + (long long)(nb + row) * 1024 + kb + scol,
                        &Blds[bb][(j * 64 + w * 16) * 32]);
        }
    };

    // fragment read geometry (swizzled read matches staged involution)
    const int arow  = lane & 15;
    const int swzco = (((lane >> 4) ^ ((arow >> 1) & 3)) * 8);  // col elems

    f32x4 acc[4][4] = {};

    stage(0, 0);
    asm volatile("s_waitcnt vmcnt(0)" ::: "memory");
    __syncthreads();

    for (int kt = 0; kt < 32; ++kt) {
        const int bb = kt & 1;
        if (kt + 1 < 32) stage(bb ^ 1, kt + 1);    // prefetch issued FIRST

        bf16x8 af[4], bfr[4];
        #pragma unroll
        for (int m = 0; m < 4; ++m)
            af[m] = *reinterpret_cast<const bf16x8*>(&Alds[bb][(wr * 64 + m * 16 + arow) * 32 + swzco]);
        #pragma unroll
        for (int n = 0; n < 4; ++n)
            bfr[n] = *reinterpret_cast<const bf16x8*>(&Blds[bb][(wc * 64 + n * 16 + arow) * 32 + swzco]);
        #pragma unroll
        for (int m = 0; m < 4; ++m)
            #pragma unroll
            for (int n = 0; n < 4; ++n)
                acc[m][n] = __builtin_amdgcn_mfma_f32_16x16x32_bf16(af[m], bfr[n], acc[m][n], 0, 0, 0);

        if (kt + 1 < 32) { asm volatile("s_waitcnt vmcnt(0)" ::: "memory"); }
        __syncthreads();                            // next tile ready, reads done
    }

    // epilogue: bias + activation (class uniform per n-tile: 512 % 128 == 0)
    const int cls = nb >> 9;             // 0=z(tanh), 1=f, 2=o (sigmoid)
    float bn[4];
    #pragma unroll
    for (int n = 0; n < 4; ++n) bn[n] = bias[nb + wc * 64 + n * 16 + arow];
    #pragma unroll
    for (int m = 0; m < 4; ++m) {
        #pragma unroll
        for (int n = 0; n < 4; ++n) {
            const int col = nb + wc * 64 + n * 16 + arow;
            #pragma unroll
            for (int j = 0; j < 4; ++j) {
                const long long row = t0 + wr * 64 + m * 16 + (lane >> 4) * 4 + j;
                float v = acc[m][n][j] + bn[n];
                v = (cls == 0) ? ftanh(v) : fsig(v);
                zfo[row * H3 + col] = f2bf(v);
            }
        }
    }
}

// ---- scan pass 1: per-chunk local scan (c_init=0) + product of f ---------
__global__ void scan_pass1(const unsigned short* __restrict__ zfo,
                           float* __restrict__ P, float* __restrict__ L) {
    const int chunk = blockIdx.x;
    const int c4    = threadIdx.x;           // 0..127
    const unsigned short* base = zfo + (long long)chunk * LC * H3 + c4 * 4;
    float c[4] = {0.f, 0.f, 0.f, 0.f};
    float p[4] = {1.f, 1.f, 1.f, 1.f};
    for (int t = 0; t < LC; ++t) {
        const unsigned short* row = base + t * H3;
        const ushort4 uz = *reinterpret_cast<const ushort4*>(row);
        const ushort4 uf = *reinterpret_cast<const ushort4*>(row + 512);
        const float z[4] = {bf2f(uz.x), bf2f(uz.y), bf2f(uz.z), bf2f(uz.w)};
        const float f[4] = {bf2f(uf.x), bf2f(uf.y), bf2f(uf.z), bf2f(uf.w)};
        #pragma unroll
        for (int j = 0; j < 4; ++j) {
            c[j] = fmaf(f[j], c[j] - z[j], z[j]);   // f*c + (1-f)*z
            p[j] *= f[j];
        }
    }
    #pragma unroll
    for (int j = 0; j < 4; ++j) {
        P[chunk * 512 + c4 * 4 + j] = p[j];
        L[chunk * 512 + c4 * 4 + j] = c[j];
    }
}

// ---- scan pass 2: parallel affine-composition scan over chunks -----------
__global__ __launch_bounds__(1024) void scan_pass2(
    const float* __restrict__ P, const float* __restrict__ L,
    float* __restrict__ carry, float* __restrict__ out) {
    const int ch = blockIdx.x;
    const int k  = threadIdx.x;
    __shared__ float sP[1024], sL[1024];
    float p = P[k * 512 + ch];
    float l = L[k * 512 + ch];
    sP[k] = p; sL[k] = l;
    __syncthreads();
    for (int d = 1; d < 1024; d <<= 1) {
        float pp = 1.f, ll = 0.f;
        if (k >= d) { pp = sP[k - d]; ll = sL[k - d]; }
        __syncthreads();
        l = fmaf(p, ll, l);
        p = p * pp;
        sP[k] = p; sL[k] = l;
        __syncthreads();
    }
    carry[k * 512 + ch] = (k == 0) ? 0.f : sL[k - 1];
    if (k == 1023) out[(long long)T_LEN * 512 + 512 + ch] = l;   // cells[-1]
}

// ---- scan pass 3: replay with carry-in, write h = o*c (float4 stores) ----
__global__ void scan_pass3(const unsigned short* __restrict__ zfo,
                           const float* __restrict__ carry,
                           float* __restrict__ out) {
    const int chunk = blockIdx.x;
    const int c4    = threadIdx.x;           // 0..127
    const unsigned short* base = zfo + (long long)chunk * LC * H3 + c4 * 4;
    float c[4], h[4] = {0.f, 0.f, 0.f, 0.f};
    #pragma unroll
    for (int j = 0; j < 4; ++j) c[j] = carry[chunk * 512 + c4 * 4 + j];
    float4* outp = reinterpret_cast<float4*>(out + (long long)chunk * LC * 512) + c4;
    for (int t = 0; t < LC; ++t) {
        const unsigned short* row = base + t * H3;
        const ushort4 uz = *reinterpret_cast<const ushort4*>(row);
        const ushort4 uf = *reinterpret_cast<const ushort4*>(row + 512);
        const ushort4 uo = *reinterpret_cast<const ushort4*>(row + 1024);
        const float z[4] = {bf2f(uz.x), bf2f(uz.y), bf2f(uz.z), bf2f(uz.w)};
        const float f[4] = {bf2f(uf.x), bf2f(uf.y), bf2f(uf.z), bf2f(uf.w)};
        const float o[4] = {bf2f(uo.x), bf2f(uo.y), bf2f(uo.z), bf2f(uo.w)};
        #pragma unroll
        for (int j = 0; j < 4; ++j) {
            c[j] = fmaf(f[j], c[j] - z[j], z[j]);
            h[j] = o[j] * c[j];
        }
        float4 hv; hv.x = h[0]; hv.y = h[1]; hv.z = h[2]; hv.w = h[3];
        outp[t * 128] = hv;
    }
    if (chunk == NCHUNK - 1) {
        #pragma unroll
        for (int j = 0; j < 4; ++j)
            out[(long long)T_LEN * 512 + c4 * 4 + j] = h[j];     // hiddens[-1]
    }
}

extern "C" void kernel_launch(void* const* d_in, const int* in_sizes, int n_in,
                              void* d_out, int out_size, void* d_ws, size_t ws_size,
                              hipStream_t stream) {
    const float* x = (const float*)d_in[0];   // [65536, 512]
    const float* W = (const float*)d_in[1];   // [1024, 1536]
    const float* b = (const float*)d_in[2];   // [1536]
    float* out = (float*)d_out;

    char* ws = (char*)d_ws;
    unsigned short* xp  = (unsigned short*)(ws);                 // 67,109,888 B (+pad)
    unsigned short* Wt  = (unsigned short*)(ws + 67110912LL);    // 3,145,728 B
    unsigned short* zfo = (unsigned short*)(ws + 70256640LL);    // 201,326,592 B
    // P/L/carry reuse the xp region (dead after GEMM)
    float* P     = (float*)(ws);
    float* L     = (float*)(ws + 4194304LL);
    float* carry = (float*)(ws + 8388608LL);

    prep_x<<<4096, 256, 0, stream>>>(x, xp);
    prep_w<<<768, 256, 0, stream>>>(W, Wt);

    dim3 gg(H3 / 128, T_LEN / 128, 1);     // 12 x 512 = 6144 blocks
    gemm_gates<<<gg, 256, 0, stream>>>(xp, Wt, b, zfo);

    scan_pass1<<<NCHUNK, 128, 0, stream>>>(zfo, P, L);
    scan_pass2<<<512, 1024, 0, stream>>>(P, L, carry, out);
    scan_pass3<<<NCHUNK, 128, 0, stream>>>(zfo, carry, out);
}

// Round 6
// 393.658 us; speedup vs baseline: 1.3229x; 1.1237x over previous
//
#include <hip/hip_runtime.h>

// QRNN fo-pool: T=65536, E=512, H=512 (kernel_size=2)
// gates[T,1536] = concat(x, shift(x)) @ W + b ; z=tanh, f,o=sigmoid
// c_t = f_t c_{t-1} + (1-f_t) z_t ; h_t = o_t c_t
// out = [hiddens (T*512) | h_last (512) | c_last (512)]  (f32)

#define T_LEN 65536
#define H3    1536
#define LC    64
#define NCHUNK 1024

typedef float f32x4 __attribute__((ext_vector_type(4)));
typedef short bf16x8 __attribute__((ext_vector_type(8)));

__device__ __forceinline__ unsigned short f2bf(float f) {
    unsigned int x = __builtin_bit_cast(unsigned int, f);
    x += 0x7fffu + ((x >> 16) & 1u);
    return (unsigned short)(x >> 16);
}
__device__ __forceinline__ float bf2f(unsigned short u) {
    return __builtin_bit_cast(float, ((unsigned int)u) << 16);
}
// fast sigmoid/tanh: v_exp_f32 (exp2) + v_rcp_f32, ~1ulp each — far below bf16 grid
__device__ __forceinline__ float fsig(float x) {
    return __builtin_amdgcn_rcpf(1.f + __builtin_amdgcn_exp2f(-1.44269504f * x));
}
__device__ __forceinline__ float ftanh(float x) {
    return 2.f * __builtin_amdgcn_rcpf(1.f + __builtin_amdgcn_exp2f(-2.88539008f * x)) - 1.f;
}

__device__ __forceinline__ void gload_lds16(const void* g, void* l) {
    __builtin_amdgcn_global_load_lds((const __attribute__((address_space(1))) void*)g,
                                     (__attribute__((address_space(3))) void*)l, 16, 0, 0);
}

// ---- prep: x (f32) -> bf16 with 512-element zero prefix ------------------
__global__ void prep_x(const float* __restrict__ x, unsigned short* __restrict__ xp) {
    const long long nq = (512LL + (long long)T_LEN * 512) / 4;
    for (long long q = (long long)blockIdx.x * blockDim.x + threadIdx.x; q < nq;
         q += (long long)gridDim.x * blockDim.x) {
        ushort4 u;
        if (q < 128) {
            u.x = 0; u.y = 0; u.z = 0; u.w = 0;
        } else {
            const float4 v = *reinterpret_cast<const float4*>(x + q * 4 - 512);
            u.x = f2bf(v.x); u.y = f2bf(v.y); u.z = f2bf(v.z); u.w = f2bf(v.w);
        }
        *reinterpret_cast<ushort4*>(xp + q * 4) = u;
    }
}

// ---- prep: W [1024,1536] f32 -> Wt [1536,1024] bf16 ----------------------
__global__ void prep_w(const float* __restrict__ W, unsigned short* __restrict__ Wt) {
    const int n_el = 1024 * H3;
    for (int i = blockIdx.x * blockDim.x + threadIdx.x; i < n_el;
         i += gridDim.x * blockDim.x) {
        const int k = i / H3, n = i - k * H3;
        Wt[n * 1024 + k] = f2bf(W[i]);
    }
}

// ---- GEMM: 128x128 tile, BK=32, 4 waves, depth-2 counted-vmcnt pipeline --
// 3 LDS buffers (48 KiB total -> 3 blocks/CU). Iter kt: stage tile kt+2 (4
// loads/thread), compute tile kt, s_waitcnt vmcnt(4) [= wait the 4 OLDEST:
// tile kt+1's loads; tile kt+2's 4 stay in flight], raw s_barrier.
// XOR swizzle 16B-slot s' = s ^ ((row>>1)&3) via pre-swizzled global source
// (linear LDS dest) + swizzled read (rule #21; same involution; 0 conflicts R4).
__global__ __launch_bounds__(256, 3) void gemm_gates(
    const unsigned short* __restrict__ xp,
    const unsigned short* __restrict__ Wt,
    const float* __restrict__ bias,
    unsigned short* __restrict__ zfo)
{
    __shared__ unsigned short Alds[3][128 * 32];
    __shared__ unsigned short Blds[3][128 * 32];

    const int tid  = threadIdx.x;
    const int lane = tid & 63;
    const int w    = tid >> 6;           // wave 0..3
    const int wr   = w >> 1, wc = w & 1; // 2x2 wave grid, 64x64 each

    // XCD-chunked swizzle (T1): 6144 blocks, 768/XCD; 12 A-panel sharers
    // land consecutively on ONE XCD; B (3 MB) L2-resident.
    const int flat = blockIdx.y * gridDim.x + blockIdx.x;   // 0..6143
    const int idx  = (flat & 7) * 768 + (flat >> 3);
    const int nb   = (idx % 12) * 128;                      // N base
    const long long t0 = (long long)(idx / 12) * 128;       // M base (time rows)

    // staging geometry: wave-uniform LDS dest + lane*16B; pre-swizzled source col
    const int srow_l = lane >> 2;                               // 0..15
    const int scol   = (((lane & 3) ^ ((lane >> 3) & 3)) * 8);  // swizzled col (elems)

    // per-lane global pointers, strength-reduced across K-tiles.
    // A col offset f(kt) = kt<16 ? 512+32*kt : 32*(kt-16); delta = +32 except
    // after staging tile 15: -992 (the concat wrap).
    const unsigned short* gA = xp + (t0 + w * 16 + srow_l) * 512 + 512 + scol;
    const unsigned short* gB = Wt + (long long)(nb + w * 16 + srow_l) * 1024 + scol;

    auto stage = [&](unsigned short* Al, unsigned short* Bl) {
        gload_lds16(gA,             Al + (w * 16) * 32);
        gload_lds16(gA + 64 * 512,  Al + ((64 + w * 16)) * 32);
        gload_lds16(gB,             Bl + (w * 16) * 32);
        gload_lds16(gB + 64 * 1024, Bl + ((64 + w * 16)) * 32);
    };

    // fragment read geometry (swizzled read matches staged involution)
    const int arow  = lane & 15;
    const int swzco = (((lane >> 4) ^ ((arow >> 1) & 3)) * 8);

    f32x4 acc[4][4] = {};

    auto compute = [&](const unsigned short* Al, const unsigned short* Bl) {
        bf16x8 af[4], bfr[4];
        #pragma unroll
        for (int m = 0; m < 4; ++m)
            af[m] = *reinterpret_cast<const bf16x8*>(Al + (wr * 64 + m * 16 + arow) * 32 + swzco);
        #pragma unroll
        for (int n = 0; n < 4; ++n)
            bfr[n] = *reinterpret_cast<const bf16x8*>(Bl + (wc * 64 + n * 16 + arow) * 32 + swzco);
        #pragma unroll
        for (int m = 0; m < 4; ++m)
            #pragma unroll
            for (int n = 0; n < 4; ++n)
                acc[m][n] = __builtin_amdgcn_mfma_f32_16x16x32_bf16(af[m], bfr[n], acc[m][n], 0, 0, 0);
    };

    // prologue: stage tiles 0 (buf0) and 1 (buf1); wait 4 oldest = tile0 done
    stage(Alds[0], Blds[0]); gA += 32; gB += 32;
    stage(Alds[1], Blds[1]); gA += 32; gB += 32;
    asm volatile("s_waitcnt vmcnt(4)" ::: "memory");
    __builtin_amdgcn_s_barrier();

    // main: kt = 0..29 in groups of 3 (buffer indices compile-time)
    for (int kt = 0; kt < 30; kt += 3) {
        {   // actual kt: stages tile kt+2 -> buf2; computes buf0
            stage(Alds[2], Blds[2]);
            gA += (kt + 2 == 15) ? -992 : 32;  gB += 32;
            compute(Alds[0], Blds[0]);
            asm volatile("s_waitcnt vmcnt(4)" ::: "memory");  // tile kt+1 landed
            __builtin_amdgcn_s_barrier();
        }
        {   // kt+1: stages tile kt+3 -> buf0; computes buf1
            stage(Alds[0], Blds[0]);
            gA += (kt + 3 == 15) ? -992 : 32;  gB += 32;
            compute(Alds[1], Blds[1]);
            asm volatile("s_waitcnt vmcnt(4)" ::: "memory");
            __builtin_amdgcn_s_barrier();
        }
        {   // kt+2: stages tile kt+4 -> buf1; computes buf2
            stage(Alds[1], Blds[1]);
            gA += (kt + 4 == 15) ? -992 : 32;  gB += 32;
            compute(Alds[2], Blds[2]);
            asm volatile("s_waitcnt vmcnt(4)" ::: "memory");
            __builtin_amdgcn_s_barrier();
        }
    }
    // kt=30: compute buf0 (tile30, landed by loop-end vmcnt(4));
    // then drain tile31's loads; kt=31: compute buf1
    compute(Alds[0], Blds[0]);
    asm volatile("s_waitcnt vmcnt(0)" ::: "memory");
    __builtin_amdgcn_s_barrier();
    compute(Alds[1], Blds[1]);

    // epilogue: bias + activation (class uniform per n-tile: 512 % 128 == 0)
    const int cls = nb >> 9;             // 0=z(tanh), 1=f, 2=o (sigmoid)
    float bn[4];
    #pragma unroll
    for (int n = 0; n < 4; ++n) bn[n] = bias[nb + wc * 64 + n * 16 + arow];
    #pragma unroll
    for (int m = 0; m < 4; ++m) {
        #pragma unroll
        for (int n = 0; n < 4; ++n) {
            const int col = nb + wc * 64 + n * 16 + arow;
            #pragma unroll
            for (int j = 0; j < 4; ++j) {
                const long long row = t0 + wr * 64 + m * 16 + (lane >> 4) * 4 + j;
                float v = acc[m][n][j] + bn[n];
                v = (cls == 0) ? ftanh(v) : fsig(v);
                zfo[row * H3 + col] = f2bf(v);
            }
        }
    }
}

// ---- scan pass 1: per-chunk local scan (c_init=0) + product of f ---------
__global__ void scan_pass1(const unsigned short* __restrict__ zfo,
                           float* __restrict__ P, float* __restrict__ L) {
    const int chunk = blockIdx.x;
    const int c4    = threadIdx.x;           // 0..127
    const unsigned short* base = zfo + (long long)chunk * LC * H3 + c4 * 4;
    float c[4] = {0.f, 0.f, 0.f, 0.f};
    float p[4] = {1.f, 1.f, 1.f, 1.f};
    for (int t = 0; t < LC; ++t) {
        const unsigned short* row = base + t * H3;
        const ushort4 uz = *reinterpret_cast<const ushort4*>(row);
        const ushort4 uf = *reinterpret_cast<const ushort4*>(row + 512);
        const float z[4] = {bf2f(uz.x), bf2f(uz.y), bf2f(uz.z), bf2f(uz.w)};
        const float f[4] = {bf2f(uf.x), bf2f(uf.y), bf2f(uf.z), bf2f(uf.w)};
        #pragma unroll
        for (int j = 0; j < 4; ++j) {
            c[j] = fmaf(f[j], c[j] - z[j], z[j]);   // f*c + (1-f)*z
            p[j] *= f[j];
        }
    }
    #pragma unroll
    for (int j = 0; j < 4; ++j) {
        P[chunk * 512 + c4 * 4 + j] = p[j];
        L[chunk * 512 + c4 * 4 + j] = c[j];
    }
}

// ---- scan pass 2: parallel affine-composition scan over chunks -----------
__global__ __launch_bounds__(1024) void scan_pass2(
    const float* __restrict__ P, const float* __restrict__ L,
    float* __restrict__ carry, float* __restrict__ out) {
    const int ch = blockIdx.x;
    const int k  = threadIdx.x;
    __shared__ float sP[1024], sL[1024];
    float p = P[k * 512 + ch];
    float l = L[k * 512 + ch];
    sP[k] = p; sL[k] = l;
    __syncthreads();
    for (int d = 1; d < 1024; d <<= 1) {
        float pp = 1.f, ll = 0.f;
        if (k >= d) { pp = sP[k - d]; ll = sL[k - d]; }
        __syncthreads();
        l = fmaf(p, ll, l);
        p = p * pp;
        sP[k] = p; sL[k] = l;
        __syncthreads();
    }
    carry[k * 512 + ch] = (k == 0) ? 0.f : sL[k - 1];
    if (k == 1023) out[(long long)T_LEN * 512 + 512 + ch] = l;   // cells[-1]
}

// ---- scan pass 3: replay with carry-in, write h = o*c (float4 stores) ----
__global__ void scan_pass3(const unsigned short* __restrict__ zfo,
                           const float* __restrict__ carry,
                           float* __restrict__ out) {
    const int chunk = blockIdx.x;
    const int c4    = threadIdx.x;           // 0..127
    const unsigned short* base = zfo + (long long)chunk * LC * H3 + c4 * 4;
    float c[4], h[4] = {0.f, 0.f, 0.f, 0.f};
    #pragma unroll
    for (int j = 0; j < 4; ++j) c[j] = carry[chunk * 512 + c4 * 4 + j];
    float4* outp = reinterpret_cast<float4*>(out + (long long)chunk * LC * 512) + c4;
    for (int t = 0; t < LC; ++t) {
        const unsigned short* row = base + t * H3;
        const ushort4 uz = *reinterpret_cast<const ushort4*>(row);
        const ushort4 uf = *reinterpret_cast<const ushort4*>(row + 512);
        const ushort4 uo = *reinterpret_cast<const ushort4*>(row + 1024);
        const float z[4] = {bf2f(uz.x), bf2f(uz.y), bf2f(uz.z), bf2f(uz.w)};
        const float f[4] = {bf2f(uf.x), bf2f(uf.y), bf2f(uf.z), bf2f(uf.w)};
        const float o[4] = {bf2f(uo.x), bf2f(uo.y), bf2f(uo.z), bf2f(uo.w)};
        #pragma unroll
        for (int j = 0; j < 4; ++j) {
            c[j] = fmaf(f[j], c[j] - z[j], z[j]);
            h[j] = o[j] * c[j];
        }
        float4 hv; hv.x = h[0]; hv.y = h[1]; hv.z = h[2]; hv.w = h[3];
        outp[t * 128] = hv;
    }
    if (chunk == NCHUNK - 1) {
        #pragma unroll
        for (int j = 0; j < 4; ++j)
            out[(long long)T_LEN * 512 + c4 * 4 + j] = h[j];     // hiddens[-1]
    }
}

extern "C" void kernel_launch(void* const* d_in, const int* in_sizes, int n_in,
                              void* d_out, int out_size, void* d_ws, size_t ws_size,
                              hipStream_t stream) {
    const float* x = (const float*)d_in[0];   // [65536, 512]
    const float* W = (const float*)d_in[1];   // [1024, 1536]
    const float* b = (const float*)d_in[2];   // [1536]
    float* out = (float*)d_out;

    char* ws = (char*)d_ws;
    unsigned short* xp  = (unsigned short*)(ws);                 // 67,109,888 B (+pad)
    unsigned short* Wt  = (unsigned short*)(ws + 67110912LL);    // 3,145,728 B
    unsigned short* zfo = (unsigned short*)(ws + 70256640LL);    // 201,326,592 B
    // P/L/carry reuse the xp region (dead after GEMM)
    float* P     = (float*)(ws);
    float* L     = (float*)(ws + 4194304LL);
    float* carry = (float*)(ws + 8388608LL);

    prep_x<<<4096, 256, 0, stream>>>(x, xp);
    prep_w<<<768, 256, 0, stream>>>(W, Wt);

    dim3 gg(H3 / 128, T_LEN / 128, 1);     // 12 x 512 = 6144 blocks
    gemm_gates<<<gg, 256, 0, stream>>>(xp, Wt, b, zfo);

    scan_pass1<<<NCHUNK, 128, 0, stream>>>(zfo, P, L);
    scan_pass2<<<512, 1024, 0, stream>>>(P, L, carry, out);
    scan_pass3<<<NCHUNK, 128, 0, stream>>>(zfo, carry, out);
}

// Round 7
// 382.880 us; speedup vs baseline: 1.3602x; 1.0281x over previous
//
#include <hip/hip_runtime.h>

// QRNN fo-pool: T=65536, E=512, H=512 (kernel_size=2)
// gates[T,1536] = concat(x, shift(x)) @ W + b ; z=tanh, f,o=sigmoid
// c_t = f_t c_{t-1} + (1-f_t) z_t ; h_t = o_t c_t
// out = [hiddens (T*512) | h_last (512) | c_last (512)]  (f32)

#define T_LEN 65536
#define H3    1536
#define LC    64
#define NCHUNK 1024

typedef float f32x4 __attribute__((ext_vector_type(4)));
typedef short bf16x8 __attribute__((ext_vector_type(8)));

__device__ __forceinline__ unsigned short f2bf(float f) {
    unsigned int x = __builtin_bit_cast(unsigned int, f);
    x += 0x7fffu + ((x >> 16) & 1u);
    return (unsigned short)(x >> 16);
}
__device__ __forceinline__ float bf2f(unsigned short u) {
    return __builtin_bit_cast(float, ((unsigned int)u) << 16);
}
// fast sigmoid/tanh: v_exp_f32 (exp2) + v_rcp_f32, ~1ulp each — far below bf16 grid
__device__ __forceinline__ float fsig(float x) {
    return __builtin_amdgcn_rcpf(1.f + __builtin_amdgcn_exp2f(-1.44269504f * x));
}
__device__ __forceinline__ float ftanh(float x) {
    return 2.f * __builtin_amdgcn_rcpf(1.f + __builtin_amdgcn_exp2f(-2.88539008f * x)) - 1.f;
}

__device__ __forceinline__ void gload_lds16(const void* g, void* l) {
    __builtin_amdgcn_global_load_lds((const __attribute__((address_space(1))) void*)g,
                                     (__attribute__((address_space(3))) void*)l, 16, 0, 0);
}

// ---- prep: x (f32) -> bf16 with 512-element zero prefix ------------------
__global__ void prep_x(const float* __restrict__ x, unsigned short* __restrict__ xp) {
    const long long nq = (512LL + (long long)T_LEN * 512) / 4;
    for (long long q = (long long)blockIdx.x * blockDim.x + threadIdx.x; q < nq;
         q += (long long)gridDim.x * blockDim.x) {
        ushort4 u;
        if (q < 128) {
            u.x = 0; u.y = 0; u.z = 0; u.w = 0;
        } else {
            const float4 v = *reinterpret_cast<const float4*>(x + q * 4 - 512);
            u.x = f2bf(v.x); u.y = f2bf(v.y); u.z = f2bf(v.z); u.w = f2bf(v.w);
        }
        *reinterpret_cast<ushort4*>(xp + q * 4) = u;
    }
}

// ---- prep: W [1024,1536] f32 -> Wt [1536,1024] bf16 ----------------------
__global__ void prep_w(const float* __restrict__ W, unsigned short* __restrict__ Wt) {
    const int n_el = 1024 * H3;
    for (int i = blockIdx.x * blockDim.x + threadIdx.x; i < n_el;
         i += gridDim.x * blockDim.x) {
        const int k = i / H3, n = i - k * H3;
        Wt[n * 1024 + k] = f2bf(W[i]);
    }
}

// ---- GEMM: 128Mx256N tile, BK=32, 4 waves of 64x128, depth-2 pipeline ----
// LDS: A[3][128*32] (8KB) + B[3][256*32] (16KB) = 72 KiB -> 2 blocks/CU.
// Iter kt: stage tile kt+2 (6 loads/thread), compute tile kt (12 ds_read +
// 32 MFMA), s_waitcnt vmcnt(6) [wait 6 oldest = tile kt+1; kt+2's 6 stay in
// flight], raw s_barrier. XOR swizzle 16B-slot s' = s ^ ((row>>1)&3) via
// pre-swizzled global source (linear LDS dest) + swizzled read (rule #21).
__global__ __launch_bounds__(256, 2) void gemm_gates(
    const unsigned short* __restrict__ xp,
    const unsigned short* __restrict__ Wt,
    const float* __restrict__ bias,
    unsigned short* __restrict__ zfo)
{
    __shared__ unsigned short Alds[3][128 * 32];
    __shared__ unsigned short Blds[3][256 * 32];

    const int tid  = threadIdx.x;
    const int lane = tid & 63;
    const int w    = tid >> 6;           // wave 0..3
    const int wm   = w >> 1, wn = w & 1; // 2x2 wave grid, each 64M x 128N

    // XCD-chunked swizzle (T1): 3072 blocks, 384/XCD; the 6 blocks sharing
    // an A-panel land consecutively on ONE XCD; B (3 MB) L2-resident.
    const int flat = blockIdx.y * gridDim.x + blockIdx.x;   // 0..3071
    const int idx  = (flat & 7) * 384 + (flat >> 3);
    const int nb   = (idx % 6) * 256;                       // N base (0..1280)
    const long long t0 = (long long)(idx / 6) * 128;        // M base (time rows)

    // staging geometry: wave-uniform LDS dest + lane*16B; pre-swizzled source col
    const int srow_l = lane >> 2;                               // 0..15
    const int scol   = (((lane & 3) ^ ((lane >> 3) & 3)) * 8);  // swizzled col (elems)

    // per-lane global pointers, strength-reduced across K-tiles.
    // A col offset f(kt) = kt<16 ? 512+32*kt : 32*(kt-16); delta = +32 except
    // after staging tile 15: -992 (the concat wrap). B: +32 always.
    const unsigned short* gA = xp + (t0 + w * 16 + srow_l) * 512 + 512 + scol;
    const unsigned short* gB = Wt + (long long)(nb + w * 16 + srow_l) * 1024 + scol;

    auto stage = [&](unsigned short* Al, unsigned short* Bl) {
        gload_lds16(gA,              Al + (w * 16) * 32);
        gload_lds16(gA + 64 * 512,   Al + (64 + w * 16) * 32);
        gload_lds16(gB,              Bl + (w * 16) * 32);
        gload_lds16(gB + 64 * 1024,  Bl + (64 + w * 16) * 32);
        gload_lds16(gB + 128 * 1024, Bl + (128 + w * 16) * 32);
        gload_lds16(gB + 192 * 1024, Bl + (192 + w * 16) * 32);
    };

    // fragment read geometry (swizzled read matches staged involution)
    const int arow  = lane & 15;
    const int swzco = (((lane >> 4) ^ ((arow >> 1) & 3)) * 8);

    f32x4 acc[4][8] = {};

    auto compute = [&](const unsigned short* Al, const unsigned short* Bl) {
        bf16x8 af[4], bfr[8];
        #pragma unroll
        for (int m = 0; m < 4; ++m)
            af[m] = *reinterpret_cast<const bf16x8*>(Al + (wm * 64 + m * 16 + arow) * 32 + swzco);
        #pragma unroll
        for (int n = 0; n < 8; ++n)
            bfr[n] = *reinterpret_cast<const bf16x8*>(Bl + (wn * 128 + n * 16 + arow) * 32 + swzco);
        #pragma unroll
        for (int n = 0; n < 8; ++n)
            #pragma unroll
            for (int m = 0; m < 4; ++m)
                acc[m][n] = __builtin_amdgcn_mfma_f32_16x16x32_bf16(af[m], bfr[n], acc[m][n], 0, 0, 0);
    };

    // prologue: stage tiles 0 (buf0), 1 (buf1); wait 6 oldest = tile0 done
    stage(Alds[0], Blds[0]); gA += 32; gB += 32;
    stage(Alds[1], Blds[1]); gA += 32; gB += 32;
    asm volatile("s_waitcnt vmcnt(6)" ::: "memory");
    __builtin_amdgcn_s_barrier();

    // main: kt = 0..29 in groups of 3 (buffer indices compile-time)
    for (int kt = 0; kt < 30; kt += 3) {
        {   // kt: stages tile kt+2 -> buf2; computes buf0
            stage(Alds[2], Blds[2]);
            gA += (kt + 2 == 15) ? -992 : 32;  gB += 32;
            compute(Alds[0], Blds[0]);
            asm volatile("s_waitcnt vmcnt(6)" ::: "memory");  // tile kt+1 landed
            __builtin_amdgcn_s_barrier();
        }
        {   // kt+1: stages tile kt+3 -> buf0; computes buf1
            stage(Alds[0], Blds[0]);
            gA += (kt + 3 == 15) ? -992 : 32;  gB += 32;
            compute(Alds[1], Blds[1]);
            asm volatile("s_waitcnt vmcnt(6)" ::: "memory");
            __builtin_amdgcn_s_barrier();
        }
        {   // kt+2: stages tile kt+4 -> buf1; computes buf2
            stage(Alds[1], Blds[1]);
            gA += (kt + 4 == 15) ? -992 : 32;  gB += 32;
            compute(Alds[2], Blds[2]);
            asm volatile("s_waitcnt vmcnt(6)" ::: "memory");
            __builtin_amdgcn_s_barrier();
        }
    }
    // kt=30: compute buf0 (tile30, landed by loop-end vmcnt(6));
    // then drain tile31's loads; kt=31: compute buf1
    compute(Alds[0], Blds[0]);
    asm volatile("s_waitcnt vmcnt(0)" ::: "memory");
    __builtin_amdgcn_s_barrier();
    compute(Alds[1], Blds[1]);

    // epilogue: bias + activation. Block spans 256 cols, class width 512,
    // nb multiple of 256 -> single class per block: cls = nb>>9.
    const int cls = nb >> 9;             // 0=z(tanh), 1=f, 2=o (sigmoid)
    #pragma unroll
    for (int n = 0; n < 8; ++n) {
        const int col = nb + wn * 128 + n * 16 + arow;
        const float bn_ = bias[col];
        #pragma unroll
        for (int m = 0; m < 4; ++m) {
            const long long row0 = t0 + wm * 64 + m * 16 + (lane >> 4) * 4;
            #pragma unroll
            for (int j = 0; j < 4; ++j) {
                float v = acc[m][n][j] + bn_;
                v = (cls == 0) ? ftanh(v) : fsig(v);
                zfo[(row0 + j) * H3 + col] = f2bf(v);
            }
        }
    }
}

// ---- scan pass 1: per-chunk local scan (c_init=0) + product of f ---------
__global__ void scan_pass1(const unsigned short* __restrict__ zfo,
                           float* __restrict__ P, float* __restrict__ L) {
    const int chunk = blockIdx.x;
    const int c4    = threadIdx.x;           // 0..127
    const unsigned short* base = zfo + (long long)chunk * LC * H3 + c4 * 4;
    float c[4] = {0.f, 0.f, 0.f, 0.f};
    float p[4] = {1.f, 1.f, 1.f, 1.f};
    for (int t = 0; t < LC; ++t) {
        const unsigned short* row = base + t * H3;
        const ushort4 uz = *reinterpret_cast<const ushort4*>(row);
        const ushort4 uf = *reinterpret_cast<const ushort4*>(row + 512);
        const float z[4] = {bf2f(uz.x), bf2f(uz.y), bf2f(uz.z), bf2f(uz.w)};
        const float f[4] = {bf2f(uf.x), bf2f(uf.y), bf2f(uf.z), bf2f(uf.w)};
        #pragma unroll
        for (int j = 0; j < 4; ++j) {
            c[j] = fmaf(f[j], c[j] - z[j], z[j]);   // f*c + (1-f)*z
            p[j] *= f[j];
        }
    }
    #pragma unroll
    for (int j = 0; j < 4; ++j) {
        P[chunk * 512 + c4 * 4 + j] = p[j];
        L[chunk * 512 + c4 * 4 + j] = c[j];
    }
}

// ---- scan pass 2: parallel affine-composition scan over chunks -----------
__global__ __launch_bounds__(1024) void scan_pass2(
    const float* __restrict__ P, const float* __restrict__ L,
    float* __restrict__ carry, float* __restrict__ out) {
    const int ch = blockIdx.x;
    const int k  = threadIdx.x;
    __shared__ float sP[1024], sL[1024];
    float p = P[k * 512 + ch];
    float l = L[k * 512 + ch];
    sP[k] = p; sL[k] = l;
    __syncthreads();
    for (int d = 1; d < 1024; d <<= 1) {
        float pp = 1.f, ll = 0.f;
        if (k >= d) { pp = sP[k - d]; ll = sL[k - d]; }
        __syncthreads();
        l = fmaf(p, ll, l);
        p = p * pp;
        sP[k] = p; sL[k] = l;
        __syncthreads();
    }
    carry[k * 512 + ch] = (k == 0) ? 0.f : sL[k - 1];
    if (k == 1023) out[(long long)T_LEN * 512 + 512 + ch] = l;   // cells[-1]
}

// ---- scan pass 3: replay with carry-in, write h = o*c (float4 stores) ----
__global__ void scan_pass3(const unsigned short* __restrict__ zfo,
                           const float* __restrict__ carry,
                           float* __restrict__ out) {
    const int chunk = blockIdx.x;
    const int c4    = threadIdx.x;           // 0..127
    const unsigned short* base = zfo + (long long)chunk * LC * H3 + c4 * 4;
    float c[4], h[4] = {0.f, 0.f, 0.f, 0.f};
    #pragma unroll
    for (int j = 0; j < 4; ++j) c[j] = carry[chunk * 512 + c4 * 4 + j];
    float4* outp = reinterpret_cast<float4*>(out + (long long)chunk * LC * 512) + c4;
    for (int t = 0; t < LC; ++t) {
        const unsigned short* row = base + t * H3;
        const ushort4 uz = *reinterpret_cast<const ushort4*>(row);
        const ushort4 uf = *reinterpret_cast<const ushort4*>(row + 512);
        const ushort4 uo = *reinterpret_cast<const ushort4*>(row + 1024);
        const float z[4] = {bf2f(uz.x), bf2f(uz.y), bf2f(uz.z), bf2f(uz.w)};
        const float f[4] = {bf2f(uf.x), bf2f(uf.y), bf2f(uf.z), bf2f(uf.w)};
        const float o[4] = {bf2f(uo.x), bf2f(uo.y), bf2f(uo.z), bf2f(uo.w)};
        #pragma unroll
        for (int j = 0; j < 4; ++j) {
            c[j] = fmaf(f[j], c[j] - z[j], z[j]);
            h[j] = o[j] * c[j];
        }
        float4 hv; hv.x = h[0]; hv.y = h[1]; hv.z = h[2]; hv.w = h[3];
        outp[t * 128] = hv;
    }
    if (chunk == NCHUNK - 1) {
        #pragma unroll
        for (int j = 0; j < 4; ++j)
            out[(long long)T_LEN * 512 + c4 * 4 + j] = h[j];     // hiddens[-1]
    }
}

extern "C" void kernel_launch(void* const* d_in, const int* in_sizes, int n_in,
                              void* d_out, int out_size, void* d_ws, size_t ws_size,
                              hipStream_t stream) {
    const float* x = (const float*)d_in[0];   // [65536, 512]
    const float* W = (const float*)d_in[1];   // [1024, 1536]
    const float* b = (const float*)d_in[2];   // [1536]
    float* out = (float*)d_out;

    char* ws = (char*)d_ws;
    unsigned short* xp  = (unsigned short*)(ws);                 // 67,109,888 B (+pad)
    unsigned short* Wt  = (unsigned short*)(ws + 67110912LL);    // 3,145,728 B
    unsigned short* zfo = (unsigned short*)(ws + 70256640LL);    // 201,326,592 B
    // P/L/carry reuse the xp region (dead after GEMM)
    float* P     = (float*)(ws);
    float* L     = (float*)(ws + 4194304LL);
    float* carry = (float*)(ws + 8388608LL);

    prep_x<<<4096, 256, 0, stream>>>(x, xp);
    prep_w<<<768, 256, 0, stream>>>(W, Wt);

    dim3 gg(H3 / 256, T_LEN / 128, 1);     // 6 x 512 = 3072 blocks
    gemm_gates<<<gg, 256, 0, stream>>>(xp, Wt, b, zfo);

    scan_pass1<<<NCHUNK, 128, 0, stream>>>(zfo, P, L);
    scan_pass2<<<512, 1024, 0, stream>>>(P, L, carry, out);
    scan_pass3<<<NCHUNK, 128, 0, stream>>>(zfo, carry, out);
}